// Round 1
// baseline (282.724 us; speedup 1.0000x reference)
//
#include <hip/hip_runtime.h>

static constexpr int NN = 100000;   // nodes
static constexpr int NE = 3200000;  // edges
static constexpr int DI = 128;
static constexpr int DH = 64;
static constexpr int DO = 32;

static constexpr int NBK  = 391;    // dst buckets (dst>>8), 391*256 >= NN
static constexpr int BCAP = 9216;   // per-bucket capacity (mean 8184, +11 sigma)
static constexpr int TILE = 8192;   // edges per block in bucket pass
static constexpr int XW1_BASE = 392;            // mega: [0,391)=bucket, 391=castw
static constexpr int XW1_BLOCKS = (NN + 63) / 64;  // 1563

typedef short short8 __attribute__((ext_vector_type(8)));  // MFMA A/B frag
typedef float f32x4  __attribute__((ext_vector_type(4)));  // MFMA C/D frag

__device__ __forceinline__ unsigned short f2bf(float f) {
    union { float f; unsigned u; } v; v.f = f;
    unsigned r = v.u + 0x7FFFu + ((v.u >> 16) & 1u);  // RNE
    return (unsigned short)(r >> 16);
}
__device__ __forceinline__ float bflo(unsigned u) {
    union { unsigned u; float f; } v; v.u = u << 16; return v.f;
}
__device__ __forceinline__ float bfhi(unsigned u) {
    union { unsigned u; float f; } v; v.u = u & 0xFFFF0000u; return v.f;
}

// ---------------- zero bucket cursors ----------------
__global__ void k_zero(int* __restrict__ p, int n) {
    int i = blockIdx.x * blockDim.x + threadIdx.x;
    if (i < n) p[i] = 0;
}

// ---------------- mega: bucket pass || xw1 GEMM (fused cast) || cast W2 -----
__global__ __launch_bounds__(256) void k_mega(
        const int* __restrict__ src, const int* __restrict__ dst,
        int* __restrict__ bcur, int* __restrict__ bstore,
        const float* __restrict__ x, const float* __restrict__ W1,
        const float* __restrict__ W2,
        unsigned short* __restrict__ w2bf, unsigned short* __restrict__ h1b) {
    __shared__ int hist[NBK];
    __shared__ int lcur[NBK];
    __shared__ int gpos[NBK];
    __shared__ int stage[TILE];
    __shared__ unsigned short bid[TILE];

    int tid = threadIdx.x;

    if (blockIdx.x < NBK) {
        // ---- role A: LDS-aggregated bucketing of edges by dst>>8 ----
        for (int i = tid; i < NBK; i += 256) hist[i] = 0;
        __syncthreads();

        int base = blockIdx.x * TILE;
        int p[32]; unsigned short bb[32];
#pragma unroll
        for (int k = 0; k < 32; ++k) {
            int e = base + k * 256 + tid;
            if (e < NE) {
                int d = dst[e], s = src[e];
                bb[k] = (unsigned short)(d >> 8);
                p[k]  = ((d & 255) << 24) | s;       // src < 2^24
                atomicAdd(&hist[bb[k]], 1);
            } else bb[k] = 0xFFFF;
        }
        __syncthreads();

        for (int i = tid; i < NBK; i += 256)
            gpos[i] = atomicAdd(&bcur[i], hist[i]);
        __syncthreads();

        if (tid < 64) {  // exclusive scan of hist (wave 0)
            int carry = 0;
            for (int c = 0; c < (NBK + 63) / 64; ++c) {
                int idx = c * 64 + tid;
                int v = (idx < NBK) ? hist[idx] : 0;
                int inc = v;
#pragma unroll
                for (int o = 1; o < 64; o <<= 1) {
                    int u = __shfl_up(inc, o, 64);
                    if (tid >= o) inc += u;
                }
                int tot = __shfl(inc, 63, 64);
                if (idx < NBK) { int ex = carry + inc - v; hist[idx] = ex; lcur[idx] = ex; }
                carry += tot;
            }
        }
        __syncthreads();

#pragma unroll
        for (int k = 0; k < 32; ++k) {
            if (bb[k] != 0xFFFF) {
                int lp = atomicAdd(&lcur[bb[k]], 1);
                stage[lp] = p[k];
                bid[lp] = bb[k];
            }
        }
        __syncthreads();

        int tcnt = min(TILE, NE - base);
        for (int i = tid; i < tcnt; i += 256) {
            int b = bid[i];
            int off = gpos[b] + (i - hist[b]);
            if (off < BCAP) bstore[b * BCAP + off] = stage[i];
        }
    } else if (blockIdx.x == NBK) {
        // ---- role B: cast W2 -> bf16 (W1 is converted in-reg by role C) ----
        for (int i = tid; i < DH * DO; i += 256) w2bf[i] = f2bf(W2[i]);
    } else {
        // ---- role C: h1b = bf16(x @ W1), fp32 inputs cast in-register ----
        int wave = tid >> 6, lane = tid & 63;
        int q = lane >> 4, m = lane & 15, o0 = wave * 16;
        int nb = (blockIdx.x - XW1_BASE) * 64;

        short8 bfr[4];  // B-frags for all 4 K-blocks (fp32 W1 -> bf16)
#pragma unroll
        for (int kb = 0; kb < 4; ++kb)
#pragma unroll
            for (int j = 0; j < 8; ++j)
                bfr[kb][j] = (short)f2bf(W1[(kb * 32 + q * 8 + j) * DH + o0 + m]);

#pragma unroll
        for (int mt = 0; mt < 4; ++mt) {
            int row = min(nb + mt * 16 + m, NN - 1);   // clamp overhang rows
            const float* xr = x + (size_t)row * DI;
            f32x4 acc = {0.f, 0.f, 0.f, 0.f};
#pragma unroll
            for (int kb = 0; kb < 4; ++kb) {
                f32x4 u0 = *(const f32x4*)(xr + kb * 32 + q * 8);
                f32x4 u1 = *(const f32x4*)(xr + kb * 32 + q * 8 + 4);
                short8 a;
                a[0] = (short)f2bf(u0.x); a[1] = (short)f2bf(u0.y);
                a[2] = (short)f2bf(u0.z); a[3] = (short)f2bf(u0.w);
                a[4] = (short)f2bf(u1.x); a[5] = (short)f2bf(u1.y);
                a[6] = (short)f2bf(u1.z); a[7] = (short)f2bf(u1.w);
                acc = __builtin_amdgcn_mfma_f32_16x16x32_bf16(a, bfr[kb], acc, 0, 0, 0);
            }
#pragma unroll
            for (int r = 0; r < 4; ++r) {
                int n = nb + mt * 16 + q * 4 + r;
                if (n < NN) h1b[(size_t)n * DH + o0 + m] = f2bf(acc[r]);  // unscaled
            }
        }
    }
}

// ---------------- per-bucket counting sort -> in-place CSR (512 thr) --------
__global__ __launch_bounds__(512) void k_bsort(
        const int* __restrict__ bcur, int* __restrict__ bstore,
        int* __restrict__ rpb, int* __restrict__ rpe, float* __restrict__ dinv) {
    __shared__ int buf[BCAP];
    __shared__ int sorted[BCAP];
    __shared__ int hist[256], scan[256], cur[256];

    int b = blockIdx.x, tid = threadIdx.x;
    int cnt = min(bcur[b], BCAP);
    int base = b * BCAP;
    for (int i = tid; i < cnt; i += 512) buf[i] = bstore[base + i];
    if (tid < 256) hist[tid] = 0;
    __syncthreads();
    for (int i = tid; i < cnt; i += 512)
        atomicAdd(&hist[((unsigned)buf[i]) >> 24], 1);
    __syncthreads();

    if (tid < 64) {  // exclusive scan of 256 bins (wave 0)
        int carry = 0;
        for (int c = 0; c < 4; ++c) {
            int idx = c * 64 + tid;
            int v = hist[idx];
            int inc = v;
#pragma unroll
            for (int o = 1; o < 64; o <<= 1) {
                int u = __shfl_up(inc, o, 64);
                if (tid >= o) inc += u;
            }
            int tot = __shfl(inc, 63, 64);
            scan[idx] = carry + inc - v;
            cur[idx]  = carry + inc - v;
            carry += tot;
        }
    }
    __syncthreads();

    if (tid < 256) {
        int n = b * 256 + tid;
        if (n < NN) {
            int beg = base + scan[tid];
            rpb[n] = beg;
            rpe[n] = beg + hist[tid];
            dinv[n] = rsqrtf(1.0f + (float)hist[tid]);
        }
    }

    for (int i = tid; i < cnt; i += 512) {
        unsigned pv = (unsigned)buf[i];
        int pos = atomicAdd(&cur[pv >> 24], 1);
        sorted[pos] = (int)(pv & 0xFFFFFF);
    }
    __syncthreads();
    for (int i = tid; i < cnt; i += 512) bstore[base + i] = sorted[i];
}

// ---------------- gather layer 1 (direct-indexed, 8-stage pipelined) --------
// Wave = 1 node. 8 q-groups of 8 lanes; each lane owns 8 dims (uint4 = 16 B).
// No shfl in the hot loop: lane loads csr[c + k*8 + q] directly (8-lane
// broadcast), then dinv + the h1 row slice. All 8 stages' loads are issued
// before any accumulation -> up to 8 uint4 loads in flight per lane.
__global__ __launch_bounds__(256) void k_gather64(
        const int* __restrict__ rpb, const int* __restrict__ rpe,
        const int* __restrict__ csr, const unsigned* __restrict__ h,
        const float* __restrict__ dinv, const float* __restrict__ b1,
        unsigned* __restrict__ tbf) {
    int wave = threadIdx.x >> 6, lane = threadIdx.x & 63;
    int q = lane >> 3, f8 = lane & 7;
    int n = blockIdx.x * 4 + wave;
    int beg = rpb[n], end = rpe[n];
    float dn = dinv[n];

    float s0 = 0.f, s1 = 0.f, s2 = 0.f, s3 = 0.f;
    float s4 = 0.f, s5 = 0.f, s6 = 0.f, s7 = 0.f;
    if (q == 0) {                       // self-loop: dinv[n]*h1[n]
        uint4 u = *(const uint4*)(h + (size_t)n * 32 + 4 * f8);
        s0 = bflo(u.x) * dn; s1 = bfhi(u.x) * dn;
        s2 = bflo(u.y) * dn; s3 = bfhi(u.y) * dn;
        s4 = bflo(u.z) * dn; s5 = bfhi(u.z) * dn;
        s6 = bflo(u.w) * dn; s7 = bfhi(u.w) * dn;
    }

// stage K: wave-uniform guard (K*8 < cnt); ragged tail handled by clamping
// the csr index and zeroing the weight, so V is always a valid finite row.
#define G64_LD(K, S, D, V)                                              \
    int S; float D = 0.f; uint4 V;                                      \
    if ((K) * 8 < cnt) {                                                \
        int slot = (K) * 8 + q;                                         \
        S = csr[c + min(slot, cnt - 1)];                                \
        D = (slot < cnt) ? dinv[S] : 0.f;                               \
        V = *(const uint4*)(h + (size_t)S * 32 + 4 * f8);               \
    }
#define G64_AC(K, D, V)                                                 \
    if ((K) * 8 < cnt) {                                                \
        s0 = fmaf(bflo(V.x), D, s0); s1 = fmaf(bfhi(V.x), D, s1);       \
        s2 = fmaf(bflo(V.y), D, s2); s3 = fmaf(bfhi(V.y), D, s3);       \
        s4 = fmaf(bflo(V.z), D, s4); s5 = fmaf(bfhi(V.z), D, s5);       \
        s6 = fmaf(bflo(V.w), D, s6); s7 = fmaf(bfhi(V.w), D, s7);       \
    }

    for (int c = beg; c < end; c += 64) {
        int cnt = min(64, end - c);
        G64_LD(0, i0, d0, v0) G64_LD(1, i1, d1, v1)
        G64_LD(2, i2, d2, v2) G64_LD(3, i3, d3, v3)
        G64_LD(4, i4, d4, v4) G64_LD(5, i5, d5, v5)
        G64_LD(6, i6, d6, v6) G64_LD(7, i7, d7, v7)
        G64_AC(0, d0, v0) G64_AC(1, d1, v1)
        G64_AC(2, d2, v2) G64_AC(3, d3, v3)
        G64_AC(4, d4, v4) G64_AC(5, d5, v5)
        G64_AC(6, d6, v6) G64_AC(7, d7, v7)
    }
#undef G64_LD
#undef G64_AC

#define RED8(m)                                                         \
    s0 += __shfl_xor(s0, m, 64); s1 += __shfl_xor(s1, m, 64);           \
    s2 += __shfl_xor(s2, m, 64); s3 += __shfl_xor(s3, m, 64);           \
    s4 += __shfl_xor(s4, m, 64); s5 += __shfl_xor(s5, m, 64);           \
    s6 += __shfl_xor(s6, m, 64); s7 += __shfl_xor(s7, m, 64);
    RED8(8) RED8(16) RED8(32)
#undef RED8

    if (q == 0) {
        float4 bA = *(const float4*)(b1 + 8 * f8);
        float4 bB = *(const float4*)(b1 + 8 * f8 + 4);
        float t0 = fmaxf(fmaf(s0, dn, bA.x), 0.f);
        float t1 = fmaxf(fmaf(s1, dn, bA.y), 0.f);
        float t2 = fmaxf(fmaf(s2, dn, bA.z), 0.f);
        float t3 = fmaxf(fmaf(s3, dn, bA.w), 0.f);
        float t4 = fmaxf(fmaf(s4, dn, bB.x), 0.f);
        float t5 = fmaxf(fmaf(s5, dn, bB.y), 0.f);
        float t6 = fmaxf(fmaf(s6, dn, bB.z), 0.f);
        float t7 = fmaxf(fmaf(s7, dn, bB.w), 0.f);
        uint4 o;
        o.x = (unsigned)f2bf(t0) | ((unsigned)f2bf(t1) << 16);
        o.y = (unsigned)f2bf(t2) | ((unsigned)f2bf(t3) << 16);
        o.z = (unsigned)f2bf(t4) | ((unsigned)f2bf(t5) << 16);
        o.w = (unsigned)f2bf(t6) | ((unsigned)f2bf(t7) << 16);
        *(uint4*)(tbf + (size_t)n * 32 + 4 * f8) = o;
    }
}

// ---------------- layer 2 GEMM (MFMA): h2b = bf16((t @ W2) * dinv) ----------
__global__ __launch_bounds__(256) void k_l2_mfma(
        const unsigned short* __restrict__ tbf, const unsigned short* __restrict__ w2bf,
        const float* __restrict__ dinv, unsigned short* __restrict__ h2b) {
    int wave = threadIdx.x >> 6, lane = threadIdx.x & 63;
    int q = lane >> 4, m = lane & 15;
    int o0 = (wave & 1) * 16, mt = wave >> 1;
    int nb = blockIdx.x * 32;

    short8 bf[2];
#pragma unroll
    for (int kb = 0; kb < 2; ++kb)
#pragma unroll
        for (int j = 0; j < 8; ++j)
            bf[kb][j] = (short)w2bf[(kb * 32 + q * 8 + j) * DO + o0 + m];

    int row = nb + mt * 16 + m;
    f32x4 acc = {0.f, 0.f, 0.f, 0.f};
#pragma unroll
    for (int kb = 0; kb < 2; ++kb) {
        short8 a = *(const short8*)(tbf + (size_t)row * DH + kb * 32 + q * 8);
        acc = __builtin_amdgcn_mfma_f32_16x16x32_bf16(a, bf[kb], acc, 0, 0, 0);
    }
#pragma unroll
    for (int r = 0; r < 4; ++r) {
        int n = nb + mt * 16 + q * 4 + r;
        if (n < NN) h2b[(size_t)n * DO + o0 + m] = f2bf(acc[r] * dinv[n]);
    }
}

// ---------------- gather layer 2 (direct-indexed, 8-stage pipelined) --------
// Same structure as k_gather64: 8 q-groups of 8 lanes, uint2 row slice
// (8 lanes x 8 B = 64 B row), h2b pre-scaled by dinv so no per-edge weight.
__global__ __launch_bounds__(256) void k_gather32(
        const int* __restrict__ rpb, const int* __restrict__ rpe,
        const int* __restrict__ csr, const unsigned* __restrict__ h,
        const float* __restrict__ dinv, const float* __restrict__ b2,
        float* __restrict__ out) {
    int wave = threadIdx.x >> 6, lane = threadIdx.x & 63;
    int q = lane >> 3, f8 = lane & 7;
    int n = blockIdx.x * 4 + wave;
    int beg = rpb[n], end = rpe[n];

    float s0 = 0.f, s1 = 0.f, s2 = 0.f, s3 = 0.f;
    if (q == 0) {                       // self-loop counted once
        uint2 u = *(const uint2*)(h + (size_t)n * 16 + 2 * f8);
        s0 = bflo(u.x); s1 = bfhi(u.x); s2 = bflo(u.y); s3 = bfhi(u.y);
    }

#define G32_LD(K, S, G, V)                                              \
    int S; float G = 0.f; uint2 V;                                      \
    if ((K) * 8 < cnt) {                                                \
        int slot = (K) * 8 + q;                                         \
        S = csr[c + min(slot, cnt - 1)];                                \
        G = (slot < cnt) ? 1.f : 0.f;                                   \
        V = *(const uint2*)(h + (size_t)S * 16 + 2 * f8);               \
    }
#define G32_AC(K, G, V)                                                 \
    if ((K) * 8 < cnt) {                                                \
        s0 = fmaf(bflo(V.x), G, s0); s1 = fmaf(bfhi(V.x), G, s1);       \
        s2 = fmaf(bflo(V.y), G, s2); s3 = fmaf(bfhi(V.y), G, s3);       \
    }

    for (int c = beg; c < end; c += 64) {
        int cnt = min(64, end - c);
        G32_LD(0, i0, g0, v0) G32_LD(1, i1, g1, v1)
        G32_LD(2, i2, g2, v2) G32_LD(3, i3, g3, v3)
        G32_LD(4, i4, g4, v4) G32_LD(5, i5, g5, v5)
        G32_LD(6, i6, g6, v6) G32_LD(7, i7, g7, v7)
        G32_AC(0, g0, v0) G32_AC(1, g1, v1)
        G32_AC(2, g2, v2) G32_AC(3, g3, v3)
        G32_AC(4, g4, v4) G32_AC(5, g5, v5)
        G32_AC(6, g6, v6) G32_AC(7, g7, v7)
    }
#undef G32_LD
#undef G32_AC

#define RED4(m)                                                         \
    s0 += __shfl_xor(s0, m, 64); s1 += __shfl_xor(s1, m, 64);           \
    s2 += __shfl_xor(s2, m, 64); s3 += __shfl_xor(s3, m, 64);
    RED4(8) RED4(16) RED4(32)
#undef RED4

    if (q == 0) {
        float dn = dinv[n];
        float4 bb = *(const float4*)(b2 + 4 * f8);
        float4 o;
        o.x = fmaf(s0, dn, bb.x);
        o.y = fmaf(s1, dn, bb.y);
        o.z = fmaf(s2, dn, bb.z);
        o.w = fmaf(s3, dn, bb.w);
        *(float4*)(out + (size_t)n * 32 + 4 * f8) = o;
    }
}

extern "C" void kernel_launch(void* const* d_in, const int* in_sizes, int n_in,
                              void* d_out, int out_size, void* d_ws, size_t ws_size,
                              hipStream_t stream) {
    const float* x  = (const float*)d_in[0];
    const float* W1 = (const float*)d_in[1];
    const float* b1 = (const float*)d_in[2];
    const float* W2 = (const float*)d_in[3];
    const float* b2 = (const float*)d_in[4];
    const int* ei  = (const int*)d_in[5];
    const int* src = ei;        // edge_index[0]
    const int* dst = ei + NE;   // edge_index[1]
    float* out = (float*)d_out;

    // workspace layout (4 B words), total ~10.3M words = 41.3 MB:
    float* ws    = (float*)d_ws;
    int*   rpb   = (int*)ws;                          // 100,352
    int*   rpe   = (int*)(ws + 100352);               // 100,352
    float* dinv  = ws + 200704;                       // 100,352
    int*   bcur  = (int*)(ws + 301056);               // 512
    int*   bstor = (int*)(ws + 301568);               // 3,603,456
    unsigned short* w2bf = (unsigned short*)(ws + 3905024);   // 2,048 bf16 (1,024 w)
    unsigned short* tbf  = (unsigned short*)(ws + 3906048);   // 100,000x64 bf16 (3.2M w)
    unsigned short* h1b  = (unsigned short*)(ws + 7106048);   // 100,000x64 bf16 (3.2M w)
    unsigned short* h2b  = h1b;   // reuse (h1b dead after gather64); 100,000x32 bf16

    k_zero     <<<2, 256, 0, stream>>>(bcur, 512);
    k_mega     <<<XW1_BASE + XW1_BLOCKS, 256, 0, stream>>>(
                    src, dst, bcur, bstor, x, W1, W2, w2bf, h1b);
    k_bsort    <<<NBK, 512, 0, stream>>>(bcur, bstor, rpb, rpe, dinv);

    k_gather64 <<<NN / 4, 256, 0, stream>>>(rpb, rpe, bstor, (const unsigned*)h1b,
                                            dinv, b1, (unsigned*)tbf);
    k_l2_mfma  <<<NN / 32, 256, 0, stream>>>(tbf, w2bf, dinv, h2b);
    k_gather32 <<<NN / 4, 256, 0, stream>>>(rpb, rpe, bstor, (const unsigned*)h2b,
                                            dinv, b2, out);
}

// Round 2
// 268.800 us; speedup vs baseline: 1.0518x; 1.0518x over previous
//
#include <hip/hip_runtime.h>

static constexpr int NN = 100000;   // nodes
static constexpr int NE = 3200000;  // edges
static constexpr int DI = 128;
static constexpr int DH = 64;
static constexpr int DO = 32;

static constexpr int NBK  = 391;    // dst buckets (dst>>8), 391*256 >= NN
static constexpr int BCAP = 9216;   // per-bucket capacity (mean 8184, +11 sigma)
static constexpr int TILE = 8192;   // edges per block in bucket pass
static constexpr int XW1_BASE = 392;            // mega: [0,391)=bucket, 391=castw
static constexpr int XW1_BLOCKS = (NN + 63) / 64;  // 1563

typedef short short8 __attribute__((ext_vector_type(8)));  // MFMA A/B frag
typedef float f32x4  __attribute__((ext_vector_type(4)));  // MFMA C/D frag

__device__ __forceinline__ unsigned short f2bf(float f) {
    union { float f; unsigned u; } v; v.f = f;
    unsigned r = v.u + 0x7FFFu + ((v.u >> 16) & 1u);  // RNE
    return (unsigned short)(r >> 16);
}
__device__ __forceinline__ float bflo(unsigned u) {
    union { unsigned u; float f; } v; v.u = u << 16; return v.f;
}
__device__ __forceinline__ float bfhi(unsigned u) {
    union { unsigned u; float f; } v; v.u = u & 0xFFFF0000u; return v.f;
}

// ---------------- zero bucket cursors ----------------
__global__ void k_zero(int* __restrict__ p, int n) {
    int i = blockIdx.x * blockDim.x + threadIdx.x;
    if (i < n) p[i] = 0;
}

// ---------------- mega: bucket pass || xw1 GEMM (fused cast) || cast W2 -----
__global__ __launch_bounds__(256) void k_mega(
        const int* __restrict__ src, const int* __restrict__ dst,
        int* __restrict__ bcur, int* __restrict__ bstore,
        const float* __restrict__ x, const float* __restrict__ W1,
        const float* __restrict__ W2,
        unsigned short* __restrict__ w2bf, unsigned short* __restrict__ h1b) {
    __shared__ int hist[NBK];
    __shared__ int lcur[NBK];
    __shared__ int gpos[NBK];
    __shared__ int stage[TILE];
    __shared__ unsigned short bid[TILE];

    int tid = threadIdx.x;

    if (blockIdx.x < NBK) {
        // ---- role A: LDS-aggregated bucketing of edges by dst>>8 ----
        for (int i = tid; i < NBK; i += 256) hist[i] = 0;
        __syncthreads();

        int base = blockIdx.x * TILE;
        int p[32]; unsigned short bb[32];
#pragma unroll
        for (int k = 0; k < 32; ++k) {
            int e = base + k * 256 + tid;
            if (e < NE) {
                int d = dst[e], s = src[e];
                bb[k] = (unsigned short)(d >> 8);
                p[k]  = ((d & 255) << 24) | s;       // src < 2^24
                atomicAdd(&hist[bb[k]], 1);
            } else bb[k] = 0xFFFF;
        }
        __syncthreads();

        for (int i = tid; i < NBK; i += 256)
            gpos[i] = atomicAdd(&bcur[i], hist[i]);
        __syncthreads();

        if (tid < 64) {  // exclusive scan of hist (wave 0)
            int carry = 0;
            for (int c = 0; c < (NBK + 63) / 64; ++c) {
                int idx = c * 64 + tid;
                int v = (idx < NBK) ? hist[idx] : 0;
                int inc = v;
#pragma unroll
                for (int o = 1; o < 64; o <<= 1) {
                    int u = __shfl_up(inc, o, 64);
                    if (tid >= o) inc += u;
                }
                int tot = __shfl(inc, 63, 64);
                if (idx < NBK) { int ex = carry + inc - v; hist[idx] = ex; lcur[idx] = ex; }
                carry += tot;
            }
        }
        __syncthreads();

#pragma unroll
        for (int k = 0; k < 32; ++k) {
            if (bb[k] != 0xFFFF) {
                int lp = atomicAdd(&lcur[bb[k]], 1);
                stage[lp] = p[k];
                bid[lp] = bb[k];
            }
        }
        __syncthreads();

        int tcnt = min(TILE, NE - base);
        for (int i = tid; i < tcnt; i += 256) {
            int b = bid[i];
            int off = gpos[b] + (i - hist[b]);
            if (off < BCAP) bstore[b * BCAP + off] = stage[i];
        }
    } else if (blockIdx.x == NBK) {
        // ---- role B: cast W2 -> bf16 (W1 is converted in-reg by role C) ----
        for (int i = tid; i < DH * DO; i += 256) w2bf[i] = f2bf(W2[i]);
    } else {
        // ---- role C: h1b = bf16(x @ W1), fp32 inputs cast in-register ----
        int wave = tid >> 6, lane = tid & 63;
        int q = lane >> 4, m = lane & 15, o0 = wave * 16;
        int nb = (blockIdx.x - XW1_BASE) * 64;

        short8 bfr[4];  // B-frags for all 4 K-blocks (fp32 W1 -> bf16)
#pragma unroll
        for (int kb = 0; kb < 4; ++kb)
#pragma unroll
            for (int j = 0; j < 8; ++j)
                bfr[kb][j] = (short)f2bf(W1[(kb * 32 + q * 8 + j) * DH + o0 + m]);

#pragma unroll
        for (int mt = 0; mt < 4; ++mt) {
            int row = min(nb + mt * 16 + m, NN - 1);   // clamp overhang rows
            const float* xr = x + (size_t)row * DI;
            f32x4 acc = {0.f, 0.f, 0.f, 0.f};
#pragma unroll
            for (int kb = 0; kb < 4; ++kb) {
                f32x4 u0 = *(const f32x4*)(xr + kb * 32 + q * 8);
                f32x4 u1 = *(const f32x4*)(xr + kb * 32 + q * 8 + 4);
                short8 a;
                a[0] = (short)f2bf(u0.x); a[1] = (short)f2bf(u0.y);
                a[2] = (short)f2bf(u0.z); a[3] = (short)f2bf(u0.w);
                a[4] = (short)f2bf(u1.x); a[5] = (short)f2bf(u1.y);
                a[6] = (short)f2bf(u1.z); a[7] = (short)f2bf(u1.w);
                acc = __builtin_amdgcn_mfma_f32_16x16x32_bf16(a, bfr[kb], acc, 0, 0, 0);
            }
#pragma unroll
            for (int r = 0; r < 4; ++r) {
                int n = nb + mt * 16 + q * 4 + r;
                if (n < NN) h1b[(size_t)n * DH + o0 + m] = f2bf(acc[r]);  // unscaled
            }
        }
    }
}

// ---------------- per-bucket counting sort -> in-place CSR (512 thr) --------
// Tail: pre-scales this block's 256 h1b rows by dinv[n], so the layer-1
// gather needs NO per-edge dinv load (halves its VMEM request count).
__global__ __launch_bounds__(512) void k_bsort(
        const int* __restrict__ bcur, int* __restrict__ bstore,
        int* __restrict__ rpb, int* __restrict__ rpe, float* __restrict__ dinv,
        unsigned* __restrict__ h1) {
    __shared__ int buf[BCAP];
    __shared__ int sorted[BCAP];
    __shared__ int hist[256], scan[256], cur[256];
    __shared__ float sdinv[256];

    int b = blockIdx.x, tid = threadIdx.x;
    int cnt = min(bcur[b], BCAP);
    int base = b * BCAP;
    for (int i = tid; i < cnt; i += 512) buf[i] = bstore[base + i];
    if (tid < 256) hist[tid] = 0;
    __syncthreads();
    for (int i = tid; i < cnt; i += 512)
        atomicAdd(&hist[((unsigned)buf[i]) >> 24], 1);
    __syncthreads();

    if (tid < 64) {  // exclusive scan of 256 bins (wave 0)
        int carry = 0;
        for (int c = 0; c < 4; ++c) {
            int idx = c * 64 + tid;
            int v = hist[idx];
            int inc = v;
#pragma unroll
            for (int o = 1; o < 64; o <<= 1) {
                int u = __shfl_up(inc, o, 64);
                if (tid >= o) inc += u;
            }
            int tot = __shfl(inc, 63, 64);
            scan[idx] = carry + inc - v;
            cur[idx]  = carry + inc - v;
            carry += tot;
        }
    }
    __syncthreads();

    if (tid < 256) {
        int n = b * 256 + tid;
        if (n < NN) {
            int beg = base + scan[tid];
            rpb[n] = beg;
            rpe[n] = beg + hist[tid];
            float dv = rsqrtf(1.0f + (float)hist[tid]);
            dinv[n] = dv;
            sdinv[tid] = dv;
        }
    }

    for (int i = tid; i < cnt; i += 512) {
        unsigned pv = (unsigned)buf[i];
        int pos = atomicAdd(&cur[pv >> 24], 1);
        sorted[pos] = (int)(pv & 0xFFFFFF);
    }
    __syncthreads();
    for (int i = tid; i < cnt; i += 512) bstore[base + i] = sorted[i];

    // ---- pre-scale h1b rows of this block's nodes: h1[n] *= dinv[n] ----
    // (sdinv visible: written before the __syncthreads above the scatter)
    for (int i = tid; i < 2048; i += 512) {          // 256 rows x 8 uint4
        int r = i >> 3, n = b * 256 + r;
        if (n < NN) {
            float dv = sdinv[r];
            uint4* p = (uint4*)h1 + (size_t)b * 2048 + i;
            uint4 u = *p;
            u.x = (unsigned)f2bf(bflo(u.x) * dv) | ((unsigned)f2bf(bfhi(u.x) * dv) << 16);
            u.y = (unsigned)f2bf(bflo(u.y) * dv) | ((unsigned)f2bf(bfhi(u.y) * dv) << 16);
            u.z = (unsigned)f2bf(bflo(u.z) * dv) | ((unsigned)f2bf(bfhi(u.z) * dv) << 16);
            u.w = (unsigned)f2bf(bflo(u.w) * dv) | ((unsigned)f2bf(bfhi(u.w) * dv) << 16);
            *p = u;
        }
    }
}

// ---------------- gather layer 1 (uint2 loads, prescaled rows) --------------
// Wave = 1 node. lane = 16*q + f4. h rows are PRE-SCALED by dinv[src], so
// sum = sum_e h[s_e] + h[n]; t = relu(dinv[n]*sum + b1). No per-edge dinv
// load -> VMEM requests in the hot loop halve vs the 274us baseline.
__global__ __launch_bounds__(256) void k_gather64(
        const int* __restrict__ rpb, const int* __restrict__ rpe,
        const int* __restrict__ csr, const unsigned* __restrict__ h,
        const float* __restrict__ dinv, const float* __restrict__ b1,
        unsigned* __restrict__ tbf) {
    int wave = threadIdx.x >> 6, lane = threadIdx.x & 63;
    int q = lane >> 4, f4 = lane & 15;
    int n = blockIdx.x * 4 + wave;
    int beg = rpb[n], end = rpe[n];
    float dn = dinv[n];

    float s0 = 0.f, s1 = 0.f, s2 = 0.f, s3 = 0.f;
    if (q == 0) {                       // self-loop: prescaled row = dinv[n]*h1[n]
        uint2 u = *(const uint2*)(h + (size_t)n * 32 + 2 * f4);
        s0 = bflo(u.x); s1 = bfhi(u.x); s2 = bflo(u.y); s3 = bfhi(u.y);
    }
    for (int c = beg; c < end; c += 64) {
        int cnt = min(64, end - c);
        int sidx = (lane < cnt) ? csr[c + lane] : 0;
        int j = 0;
        for (; j + 16 <= cnt; j += 16) {   // 16 edges/iter, 4 loads/lane in flight
            int sa = __shfl(sidx, j + q, 64);
            int sb = __shfl(sidx, j + 4 + q, 64);
            int sc = __shfl(sidx, j + 8 + q, 64);
            int sd = __shfl(sidx, j + 12 + q, 64);
            uint2 ua = *(const uint2*)(h + (size_t)sa * 32 + 2 * f4);
            uint2 ub = *(const uint2*)(h + (size_t)sb * 32 + 2 * f4);
            uint2 uc = *(const uint2*)(h + (size_t)sc * 32 + 2 * f4);
            uint2 ud = *(const uint2*)(h + (size_t)sd * 32 + 2 * f4);
            s0 += bflo(ua.x); s1 += bfhi(ua.x); s2 += bflo(ua.y); s3 += bfhi(ua.y);
            s0 += bflo(ub.x); s1 += bfhi(ub.x); s2 += bflo(ub.y); s3 += bfhi(ub.y);
            s0 += bflo(uc.x); s1 += bfhi(uc.x); s2 += bflo(uc.y); s3 += bfhi(uc.y);
            s0 += bflo(ud.x); s1 += bfhi(ud.x); s2 += bflo(ud.y); s3 += bfhi(ud.y);
        }
        for (; j + 8 <= cnt; j += 8) {     // 8-edge step
            int sa = __shfl(sidx, j + q, 64);
            int sb = __shfl(sidx, j + 4 + q, 64);
            uint2 ua = *(const uint2*)(h + (size_t)sa * 32 + 2 * f4);
            uint2 ub = *(const uint2*)(h + (size_t)sb * 32 + 2 * f4);
            s0 += bflo(ua.x); s1 += bfhi(ua.x); s2 += bflo(ua.y); s3 += bfhi(ua.y);
            s0 += bflo(ub.x); s1 += bfhi(ub.x); s2 += bflo(ub.y); s3 += bfhi(ub.y);
        }
        for (; j < cnt; j += 4) {          // tail, predicated
            int slot = j + q;              // j<=60, q<=3 -> slot<=63, shfl safe
            int s = __shfl(sidx, slot, 64);
            if (slot < cnt) {
                uint2 u = *(const uint2*)(h + (size_t)s * 32 + 2 * f4);
                s0 += bflo(u.x); s1 += bfhi(u.x); s2 += bflo(u.y); s3 += bfhi(u.y);
            }
        }
    }
    s0 += __shfl_xor(s0, 32, 64); s1 += __shfl_xor(s1, 32, 64);
    s2 += __shfl_xor(s2, 32, 64); s3 += __shfl_xor(s3, 32, 64);
    s0 += __shfl_xor(s0, 16, 64); s1 += __shfl_xor(s1, 16, 64);
    s2 += __shfl_xor(s2, 16, 64); s3 += __shfl_xor(s3, 16, 64);
    if (q == 0) {
        float t0 = fmaxf(fmaf(s0, dn, b1[4 * f4 + 0]), 0.f);
        float t1 = fmaxf(fmaf(s1, dn, b1[4 * f4 + 1]), 0.f);
        float t2 = fmaxf(fmaf(s2, dn, b1[4 * f4 + 2]), 0.f);
        float t3 = fmaxf(fmaf(s3, dn, b1[4 * f4 + 3]), 0.f);
        uint2 o;
        o.x = (unsigned)f2bf(t0) | ((unsigned)f2bf(t1) << 16);
        o.y = (unsigned)f2bf(t2) | ((unsigned)f2bf(t3) << 16);
        *(uint2*)(tbf + (size_t)n * 32 + 2 * f4) = o;
    }
}

// ---------------- layer 2 GEMM (MFMA): h2b = bf16((t @ W2) * dinv) ----------
__global__ __launch_bounds__(256) void k_l2_mfma(
        const unsigned short* __restrict__ tbf, const unsigned short* __restrict__ w2bf,
        const float* __restrict__ dinv, unsigned short* __restrict__ h2b) {
    int wave = threadIdx.x >> 6, lane = threadIdx.x & 63;
    int q = lane >> 4, m = lane & 15;
    int o0 = (wave & 1) * 16, mt = wave >> 1;
    int nb = blockIdx.x * 32;

    short8 bf[2];
#pragma unroll
    for (int kb = 0; kb < 2; ++kb)
#pragma unroll
        for (int j = 0; j < 8; ++j)
            bf[kb][j] = (short)w2bf[(kb * 32 + q * 8 + j) * DO + o0 + m];

    int row = nb + mt * 16 + m;
    f32x4 acc = {0.f, 0.f, 0.f, 0.f};
#pragma unroll
    for (int kb = 0; kb < 2; ++kb) {
        short8 a = *(const short8*)(tbf + (size_t)row * DH + kb * 32 + q * 8);
        acc = __builtin_amdgcn_mfma_f32_16x16x32_bf16(a, bf[kb], acc, 0, 0, 0);
    }
#pragma unroll
    for (int r = 0; r < 4; ++r) {
        int n = nb + mt * 16 + q * 4 + r;
        if (n < NN) h2b[(size_t)n * DO + o0 + m] = f2bf(acc[r] * dinv[n]);
    }
}

// ---------------- gather layer 2 (uint2 loads, 8-slot MLP) ------------------
__global__ __launch_bounds__(256) void k_gather32(
        const int* __restrict__ rpb, const int* __restrict__ rpe,
        const int* __restrict__ csr, const unsigned* __restrict__ h,
        const float* __restrict__ dinv, const float* __restrict__ b2,
        float* __restrict__ out) {
    int wave = threadIdx.x >> 6, lane = threadIdx.x & 63;
    int q = lane >> 3, f4 = lane & 7;
    int n = blockIdx.x * 4 + wave;
    int beg = rpb[n], end = rpe[n];

    float s0 = 0.f, s1 = 0.f, s2 = 0.f, s3 = 0.f;
    if (q == 0) {                       // self-loop counted once
        uint2 u = *(const uint2*)(h + (size_t)n * 16 + 2 * f4);
        s0 = bflo(u.x); s1 = bfhi(u.x); s2 = bflo(u.y); s3 = bfhi(u.y);
    }
    for (int c = beg; c < end; c += 64) {
        int cnt = min(64, end - c);
        int sidx = (lane < cnt) ? csr[c + lane] : 0;
        int j = 0;
        for (; j + 16 <= cnt; j += 16) {  // 16 edges/iter, 2 loads/lane
            int sa = __shfl(sidx, j + q, 64);
            int sb = __shfl(sidx, j + 8 + q, 64);
            uint2 ua = *(const uint2*)(h + (size_t)sa * 16 + 2 * f4);
            uint2 ub = *(const uint2*)(h + (size_t)sb * 16 + 2 * f4);
            s0 += bflo(ua.x); s1 += bfhi(ua.x); s2 += bflo(ua.y); s3 += bfhi(ua.y);
            s0 += bflo(ub.x); s1 += bfhi(ub.x); s2 += bflo(ub.y); s3 += bfhi(ub.y);
        }
        for (; j < cnt; j += 8) {         // tail, predicated
            int slot = j + q;             // j<=56, q<=7 -> slot<=63, shfl safe
            int s = __shfl(sidx, slot, 64);
            if (slot < cnt) {
                uint2 u = *(const uint2*)(h + (size_t)s * 16 + 2 * f4);
                s0 += bflo(u.x); s1 += bfhi(u.x); s2 += bflo(u.y); s3 += bfhi(u.y);
            }
        }
    }
    s0 += __shfl_xor(s0, 32, 64); s1 += __shfl_xor(s1, 32, 64);
    s2 += __shfl_xor(s2, 32, 64); s3 += __shfl_xor(s3, 32, 64);
    s0 += __shfl_xor(s0, 16, 64); s1 += __shfl_xor(s1, 16, 64);
    s2 += __shfl_xor(s2, 16, 64); s3 += __shfl_xor(s3, 16, 64);
    s0 += __shfl_xor(s0, 8, 64);  s1 += __shfl_xor(s1, 8, 64);
    s2 += __shfl_xor(s2, 8, 64);  s3 += __shfl_xor(s3, 8, 64);
    if (q == 0) {
        float dn = dinv[n];
        size_t o = (size_t)n * 32 + 4 * f4;
        out[o + 0] = fmaf(s0, dn, b2[4 * f4 + 0]);
        out[o + 1] = fmaf(s1, dn, b2[4 * f4 + 1]);
        out[o + 2] = fmaf(s2, dn, b2[4 * f4 + 2]);
        out[o + 3] = fmaf(s3, dn, b2[4 * f4 + 3]);
    }
}

extern "C" void kernel_launch(void* const* d_in, const int* in_sizes, int n_in,
                              void* d_out, int out_size, void* d_ws, size_t ws_size,
                              hipStream_t stream) {
    const float* x  = (const float*)d_in[0];
    const float* W1 = (const float*)d_in[1];
    const float* b1 = (const float*)d_in[2];
    const float* W2 = (const float*)d_in[3];
    const float* b2 = (const float*)d_in[4];
    const int* ei  = (const int*)d_in[5];
    const int* src = ei;        // edge_index[0]
    const int* dst = ei + NE;   // edge_index[1]
    float* out = (float*)d_out;

    // workspace layout (4 B words), total ~10.3M words = 41.3 MB:
    float* ws    = (float*)d_ws;
    int*   rpb   = (int*)ws;                          // 100,352
    int*   rpe   = (int*)(ws + 100352);               // 100,352
    float* dinv  = ws + 200704;                       // 100,352
    int*   bcur  = (int*)(ws + 301056);               // 512
    int*   bstor = (int*)(ws + 301568);               // 3,603,456
    unsigned short* w2bf = (unsigned short*)(ws + 3905024);   // 2,048 bf16 (1,024 w)
    unsigned short* tbf  = (unsigned short*)(ws + 3906048);   // 100,000x64 bf16 (3.2M w)
    unsigned short* h1b  = (unsigned short*)(ws + 7106048);   // 100,000x64 bf16 (3.2M w)
    unsigned short* h2b  = h1b;   // reuse (h1b dead after gather64); 100,000x32 bf16

    k_zero     <<<2, 256, 0, stream>>>(bcur, 512);
    k_mega     <<<XW1_BASE + XW1_BLOCKS, 256, 0, stream>>>(
                    src, dst, bcur, bstor, x, W1, W2, w2bf, h1b);
    k_bsort    <<<NBK, 512, 0, stream>>>(bcur, bstor, rpb, rpe, dinv,
                                         (unsigned*)h1b);

    k_gather64 <<<NN / 4, 256, 0, stream>>>(rpb, rpe, bstor, (const unsigned*)h1b,
                                            dinv, b1, (unsigned*)tbf);
    k_l2_mfma  <<<NN / 32, 256, 0, stream>>>(tbf, w2bf, dinv, h2b);
    k_gather32 <<<NN / 4, 256, 0, stream>>>(rpb, rpe, bstor, (const unsigned*)h2b,
                                            dinv, b2, out);
}